// Round 16
// baseline (2001.543 us; speedup 1.0000x reference)
//
#include <hip/hip_runtime.h>
#include <hip/hip_bf16.h>

// SRNN: x_{t+1} = x + DT*(-x + J@rates + inp), rates = 0.5*(1+tanh(x)),
// out[p,t] = (w_out @ rates_t)[p] / N.
//
// v16 = v15 with PHASE GRANULARITY halved (the one un-isolated variable):
//  - BK=256, 8 phases (was BK=128, 16). Per phase per wave: 6 staging
//    loads, 8 ds_read_b128, 4 MFMA 32x32x16 (slices 4kq..4kq+3).
//  - 3 bufs x 48KB = 144KB. Counted protocol: vmcnt(6) [retire stage ph,
//    keep ph+1 in flight] -> s_barrier -> issue stage(ph+2) AFTER barrier
//    (WAR-safe: buf[(ph+2)%3]'s readers ran in iter ph-1, before barrier
//    ph which all waves passed) -> sched_barrier -> reads+MFMA.
//    NOT v13's 2-buf drain-to-0 (that cost +330us).
//  - rows now 512B (32 chunks); XOR-16 swizzle unchanged (c^(row&15)).
//  - epilogue + 4-plane kq-reduce + slab transpose: v15 verbatim.
//  - eliminated: occupancy (v14), depth (v15), drain (v13), LDS B/MAC
//    (v12 vs v10), shape (v12). This isolates phase-sync overhead.
// [history: sparse 2114-2360; coop/persistent dead ends; v9 2119; v10 1972;
//  v12 1931 (best); v13 2264; v14 1982; v15 1942.]

#define NN 2048
#define PP 256
#define DT_C 0.1f
#define ON_TIME_C 10

typedef __attribute__((ext_vector_type(8)))  short bf16x8;
typedef __attribute__((ext_vector_type(16))) float f32x16;

__device__ __forceinline__ unsigned short bf16rne(float f) {
    unsigned b = __float_as_uint(f);
    return (unsigned short)((b + 0x7FFFu + ((b >> 16) & 1u)) >> 16);
}
// 32x32x16 fragment permutation within a 16-k group (v12-verified).
__device__ __forceinline__ int kperm16(int s) {
    return (s & 3) + (((s >> 2) & 1) << 3) + ((s >> 3) << 2);
}

// ---- J f32 [N][N] -> bf16 [N][N], k-permuted per 16-group ----
__global__ void convert_J_kernel(const float* __restrict__ J,
                                 unsigned short* __restrict__ Jp) {
    int i = blockIdx.x * blockDim.x + threadIdx.x;   // grid covers NN*NN
    int row = i >> 11, k = i & 2047;
    Jp[((size_t)row << 11) + (k & ~15) + kperm16(k & 15)] = bf16rne(J[i]);
}

// ---- x = 0, rates_T = bf16(0.5) (perm-invariant), out = 0 ----
__global__ void init_kernel(float* __restrict__ x,
                            unsigned short* __restrict__ rT,
                            float* __restrict__ out, int nout) {
    int i = blockIdx.x * blockDim.x + threadIdx.x;   // grid covers NN*PP
    x[i] = 0.0f;
    rT[i] = 0x3F00;
    if (i < nout) out[i] = 0.0f;
}

#define AS1 __attribute__((address_space(1)))
#define AS3 __attribute__((address_space(3)))
#define GLOAD16(g, l) \
    __builtin_amdgcn_global_load_lds((const AS1 void*)(g), (AS3 void*)(l), 16, 0, 0)

// ---- One time step. grid 256 (1/CU), 512 thr (8 waves, 2/SIMD).
// BM=64 BN=32 BK=256, 8 phases, 3-buf LDS (3 x 48KB = 144KB). ----
__global__ __launch_bounds__(512, 1) void gemm_step_kernel(
    const unsigned short* __restrict__ Jp,    // [N][N] bf16 kperm16'd
    const unsigned short* __restrict__ rin,   // rates_T [P][N] bf16 kperm16'd
    unsigned short* __restrict__ rout,        // rates_T [P][N]
    float* __restrict__ x, const float* __restrict__ patterns,
    const float* __restrict__ w_out, float* __restrict__ out,
    int t, int T, int with_input) {

    __shared__ char smem[147456];             // 3 bufs x (A 32KB + B 16KB)

    const int tid  = threadIdx.x;
    const int w    = tid >> 6;                // wave 0..7
    const int lane = tid & 63;
    const int s    = w >> 2;                  // m-half (32 rows)
    const int kq   = w & 3;                   // K-quarter role
    const int h    = lane >> 5;               // chunk-half within k16 frag

    // XCD-contiguous swizzle: XCD owns 4 contiguous m-panels.
    const int bid   = (blockIdx.x & 7) * 32 + (blockIdx.x >> 3);
    const int mbase = (bid >> 3) * 64;
    const int nbase = (bid & 7) * 32;

    // ---- staging: stage = 512B per row (32 chunks). 48 loads/block/stage:
    // A: 32 loads (2 rows each), B: 16 loads. Wave w: A loads w*4+j (j<4),
    // B loads w*2+j (j<2). Dest = wave-uniform base + lane*16. ----
    const int p32 = lane & 31;                // chunk within row
    const char* gA[4]; int ldsA[4];
    #pragma unroll
    for (int j = 0; j < 4; ++j) {
        int li   = w * 4 + j;                 // A load index 0..31
        int arow = 2 * li + (lane >> 5);      // local m-row 0..63
        gA[j] = (const char*)Jp + (((size_t)(mbase + arow)) << 12)
                + ((p32 ^ (arow & 15)) << 4);
        ldsA[j] = li * 1024;
    }
    const char* gB[2]; int ldsB[2];
    #pragma unroll
    for (int j = 0; j < 2; ++j) {
        int li   = w * 2 + j;                 // B load index 0..15
        int brow = 2 * li + (lane >> 5);      // local n-row 0..31
        gB[j] = (const char*)rin + (((size_t)(nbase + brow)) << 12)
                + ((p32 ^ (brow & 15)) << 4);
        ldsB[j] = 32768 + li * 1024;
    }

    // ---- fragment read rows ----
    const int rA  = 32 * s + (lane & 31);     // A row (local, 0..63)
    const int rBn = lane & 31;                // B row (local n, 0..31)

    // ---- epilogue operand PREFETCH (v15) ----
    const int e_s2 = tid >> 8, e_rr = (tid >> 3) & 31, e_c4 = (tid & 7) * 4;
    const int e_mloc = e_s2 * 32 + e_rr;
    const int e_m  = mbase + e_mloc;
    const int e_n0 = nbase + e_c4;
    const size_t e_xo = ((size_t)e_m << 8) + e_n0;
    float4 e_xv = *(const float4*)(x + e_xo);
    float4 e_pv = make_float4(0.f, 0.f, 0.f, 0.f);
    if (with_input) e_pv = *(const float4*)(patterns + e_xo);
    float e_wsc = (w_out[e_m] != 0.0f) ? (1.0f / (float)NN) : 0.0f;

    f32x16 acc = {};

    // prologue: stage phases 0,1 -> bufs 0,1 (6 loads/wave each)
    #pragma unroll
    for (int ps = 0; ps < 2; ++ps) {
        const int bo = ps * 49152;
        #pragma unroll
        for (int j = 0; j < 4; ++j) GLOAD16(gA[j] + ps * 512, smem + bo + ldsA[j]);
        #pragma unroll
        for (int j = 0; j < 2; ++j) GLOAD16(gB[j] + ps * 512, smem + bo + ldsB[j]);
    }

    // ---- K-loop: 8 phases of BK=256; wave computes k16 slices 4kq..4kq+3 ----
    #pragma unroll
    for (int ph = 0; ph < 8; ++ph) {
        // counted wait: retire stage(ph); stage(ph+1)'s 6 stay in flight.
        if (ph < 7) asm volatile("s_waitcnt vmcnt(6)" ::: "memory");
        else        asm volatile("s_waitcnt vmcnt(0)" ::: "memory");
        __builtin_amdgcn_s_barrier();         // all waves' stage(ph) visible
        if (ph < 6) {                         // issue stage(ph+2) post-barrier
            const int bo = ((ph + 2) % 3) * 49152;
            #pragma unroll
            for (int j = 0; j < 4; ++j)
                GLOAD16(gA[j] + (ph + 2) * 512, smem + bo + ldsA[j]);
            #pragma unroll
            for (int j = 0; j < 2; ++j)
                GLOAD16(gB[j] + (ph + 2) * 512, smem + bo + ldsB[j]);
        }
        __builtin_amdgcn_sched_barrier(0);    // keep reads below barrier

        const int bb = (ph % 3) * 49152;
        #pragma unroll
        for (int sl = 0; sl < 4; ++sl) {
            const int c = kq * 8 + sl * 2 + h;    // 16B chunk in 512B row
            bf16x8 a = *(const bf16x8*)(smem + bb + rA * 512
                                        + ((c ^ (rA & 15)) << 4));
            bf16x8 b = *(const bf16x8*)(smem + bb + 32768 + rBn * 512
                                        + ((c ^ (rBn & 15)) << 4));
            acc = __builtin_amdgcn_mfma_f32_32x32x16_bf16(a, b, acc, 0, 0, 0);
        }
    }

    __syncthreads();                          // all reads done; reuse smem

    // ---- write kq-partials: plane (s*4+kq), [32 row][32 col] f32 = 32KB ----
    {
        float* pf = (float*)smem;
        const int plane = (s * 4 + kq) * 1024;
        #pragma unroll
        for (int reg = 0; reg < 16; ++reg) {
            int row = (reg & 3) + 8 * (reg >> 2) + 4 * h;   // v12-verified
            pf[plane + row * 32 + (lane & 31)] = acc[reg];
        }
    }
    __syncthreads();

    // ---- reduce 4 kq-planes + epilogue (prefetched operands, v15) ----
    {
        const float4* pf4 = (const float4*)smem;
        int base = ((e_s2 * 4) * 1024 + e_rr * 32 + e_c4) >> 2;  // float4 idx
        float4 v0 = pf4[base], v1 = pf4[base + 256];
        float4 v2 = pf4[base + 512], v3 = pf4[base + 768];
        float sum[4] = {v0.x + v1.x + v2.x + v3.x, v0.y + v1.y + v2.y + v3.y,
                        v0.z + v1.z + v2.z + v3.z, v0.w + v1.w + v2.w + v3.w};

        float xn[4] = {e_xv.x + DT_C * (sum[0] + e_pv.x - e_xv.x),
                       e_xv.y + DT_C * (sum[1] + e_pv.y - e_xv.y),
                       e_xv.z + DT_C * (sum[2] + e_pv.z - e_xv.z),
                       e_xv.w + DT_C * (sum[3] + e_pv.w - e_xv.w)};
        *(float4*)(x + e_xo) = make_float4(xn[0], xn[1], xn[2], xn[3]);

        const int pos = (e_mloc & ~15) + kperm16(e_mloc & 15);
        #pragma unroll
        for (int j = 0; j < 4; ++j) {
            float r = 0.5f * (1.0f + tanhf(xn[j]));
            if (e_wsc != 0.0f)
                atomicAdd(&out[(size_t)(e_n0 + j) * T + t], r * e_wsc);
            int nloc = e_c4 + j;
            int byte = 32768 + nloc * 128
                     + (((pos >> 3) ^ (nloc & 7)) << 4) + (pos & 7) * 2;
            *(unsigned short*)(smem + byte) = bf16rne(r);
        }
    }
    __syncthreads();
    if (tid < 256) {   // linear write-out of the block's [32 n][64 m] slab
        int nl = tid >> 3, pc = tid & 7;
        uint4 v = *(const uint4*)(smem + 32768 + nl * 128 + ((pc ^ (nl & 7)) << 4));
        *(uint4*)((char*)rout + (((size_t)(nbase + nl)) << 12) + mbase * 2 + pc * 16) = v;
    }
}

extern "C" void kernel_launch(void* const* d_in, const int* in_sizes, int n_in,
                              void* d_out, int out_size, void* d_ws, size_t ws_size,
                              hipStream_t stream) {
    const float* patterns = (const float*)d_in[0];   // [N, P]
    const float* J        = (const float*)d_in[1];   // [N, N]
    const float* w_out    = (const float*)d_in[2];   // [N]
    float* out            = (float*)d_out;           // [P, T]

    int T = out_size / PP;                           // 200

    size_t off = 0;
    auto alloc = [&](size_t bytes) {
        void* p = (char*)d_ws + off;
        off += (bytes + 255) & ~(size_t)255;
        return p;
    };
    unsigned short* Jp = (unsigned short*)alloc((size_t)NN * NN * 2);  // 8MB
    unsigned short* r0 = (unsigned short*)alloc((size_t)PP * NN * 2);  // 1MB
    unsigned short* r1 = (unsigned short*)alloc((size_t)PP * NN * 2);  // 1MB
    float*          x  = (float*)         alloc((size_t)NN * PP * 4);  // 2MB
    (void)ws_size; (void)n_in; (void)in_sizes;

    convert_J_kernel<<<(NN * NN) / 256, 256, 0, stream>>>(J, Jp);
    init_kernel<<<(NN * PP) / 256, 256, 0, stream>>>(x, r0, out, PP * T);

    for (int t = 0; t < T; ++t) {
        const unsigned short* rin = (t & 1) ? r1 : r0;
        unsigned short*      rout = (t & 1) ? r0 : r1;
        gemm_step_kernel<<<256, 512, 0, stream>>>(Jp, rin, rout, x, patterns,
                                                  w_out, out, t, T,
                                                  (t < ON_TIME_C) ? 1 : 0);
    }
}

// Round 17
// 1936.217 us; speedup vs baseline: 1.0337x; 1.0337x over previous
//
#include <hip/hip_runtime.h>
#include <hip/hip_bf16.h>

// SRNN: x_{t+1} = x + DT*(-x + J@rates + inp), rates = 0.5*(1+tanh(x)),
// out[p,t] = (w_out @ rates_t)[p] / N.
//
// v17 = v12 RESTORED (best measured: 1931us). Dense bf16 MFMA per step,
// 32x32x16, BM=64 BN=32 BK=128, 16 phases, 8 waves (2/SIMD), 4-buf LDS,
// counted vmcnt(6/3/0), issue-stage(ph+2)-before-wait, XOR-16 chunk
// swizzle, kperm16 J layout, XCD-contiguous m-panels, fused epilogue
// (x-update, tanh, atomic sparse readout, rates_T LDS transpose).
//
// Elimination matrix (rounds 9-16): occupancy x2 (v14 null), pipeline
// depth x2 (v15 null), phase count /2 (v16 -3.5%), drain-to-0 (v13 -15%),
// LDS B/MAC /2 (v12 -2%), persistent cg-sync (125us/step), custom barrier
// (22.5us/step). Remaining structure: ~7us kernel (L2 2.9 + sync/latency
// residual) + ~2.5us runtime launch tax per dependent dispatch x 200.

#define NN 2048
#define PP 256
#define DT_C 0.1f
#define ON_TIME_C 10

typedef __attribute__((ext_vector_type(8)))  short bf16x8;
typedef __attribute__((ext_vector_type(16))) float f32x16;

__device__ __forceinline__ unsigned short bf16rne(float f) {
    unsigned b = __float_as_uint(f);
    return (unsigned short)((b + 0x7FFFu + ((b >> 16) & 1u)) >> 16);
}
// 32x32x16 fragment permutation within a 16-k group (bit-exactness
// verified: v12 reproduced v10's absmax exactly).
__device__ __forceinline__ int kperm16(int s) {
    return (s & 3) + (((s >> 2) & 1) << 3) + ((s >> 3) << 2);
}

// ---- J f32 [N][N] -> bf16 [N][N], k-permuted per 16-group ----
__global__ void convert_J_kernel(const float* __restrict__ J,
                                 unsigned short* __restrict__ Jp) {
    int i = blockIdx.x * blockDim.x + threadIdx.x;   // grid covers NN*NN
    int row = i >> 11, k = i & 2047;
    Jp[((size_t)row << 11) + (k & ~15) + kperm16(k & 15)] = bf16rne(J[i]);
}

// ---- x = 0, rates_T = bf16(0.5) (perm-invariant), out = 0 ----
__global__ void init_kernel(float* __restrict__ x,
                            unsigned short* __restrict__ rT,
                            float* __restrict__ out, int nout) {
    int i = blockIdx.x * blockDim.x + threadIdx.x;   // grid covers NN*PP
    x[i] = 0.0f;
    rT[i] = 0x3F00;
    if (i < nout) out[i] = 0.0f;
}

#define AS1 __attribute__((address_space(1)))
#define AS3 __attribute__((address_space(3)))
#define GLOAD16(g, l) \
    __builtin_amdgcn_global_load_lds((const AS1 void*)(g), (AS3 void*)(l), 16, 0, 0)

// ---- One time step. grid 256 (1/CU), 512 thr (8 waves). BM=64 BN=32. ----
__global__ __launch_bounds__(512, 1) void gemm_step_kernel(
    const unsigned short* __restrict__ Jp,    // [N][N] bf16 kperm16'd
    const unsigned short* __restrict__ rin,   // rates_T [P][N] bf16 kperm16'd
    unsigned short* __restrict__ rout,        // rates_T [P][N]
    float* __restrict__ x, const float* __restrict__ patterns,
    const float* __restrict__ w_out, float* __restrict__ out,
    int t, int T, int with_input) {

    __shared__ char smem[98304];              // 4 bufs x (A 16KB + B 8KB)

    const int tid  = threadIdx.x;
    const int w    = tid >> 6;                // wave 0..7
    const int lane = tid & 63;
    const int s    = w >> 2;                  // m-half (32 rows)
    const int kq   = w & 3;                   // K-quarter role
    const int h    = lane >> 5;               // chunk-half within k16 frag

    // XCD-contiguous swizzle: XCD owns 4 contiguous m-panels.
    const int bid   = (blockIdx.x & 7) * 32 + (blockIdx.x >> 3);
    const int mbase = (bid >> 3) * 64;
    const int nbase = (bid & 7) * 32;

    // ---- staging: wave stages A rows 8w..8w+7 (2 loads), B rows 4w..4w+3 ----
    const int rA0 = 8 * w + (lane >> 4);
    const int rA1 = rA0 + 4;
    const int rB  = 4 * w + (lane >> 4);
    const char* gA0 = (const char*)Jp  + (((size_t)(mbase + rA0)) << 12)
                      + (((lane & 15) ^ (rA0 & 15)) << 4);
    const char* gA1 = (const char*)Jp  + (((size_t)(mbase + rA1)) << 12)
                      + (((lane & 15) ^ (rA1 & 15)) << 4);
    const char* gB  = (const char*)rin + (((size_t)(nbase + rB )) << 12)
                      + (((lane & 15) ^ (rB  & 15)) << 4);
    const int ldsA0 = (8 * w) * 256, ldsA1 = (8 * w + 4) * 256;
    const int ldsB  = 16384 + 4 * w * 256;

    // ---- fragment read rows ----
    const int rA  = 32 * s + (lane & 31);     // A row (local, 0..63)
    const int rBn = lane & 31;                // B row (local n, 0..31)

    f32x16 acc = {};

    // prologue: stage phases 0,1
    GLOAD16(gA0,       smem + 0 * 24576 + ldsA0);
    GLOAD16(gA1,       smem + 0 * 24576 + ldsA1);
    GLOAD16(gB,        smem + 0 * 24576 + ldsB);
    GLOAD16(gA0 + 256, smem + 1 * 24576 + ldsA0);
    GLOAD16(gA1 + 256, smem + 1 * 24576 + ldsA1);
    GLOAD16(gB  + 256, smem + 1 * 24576 + ldsB);

    // ---- K-loop: 16 phases of BK=128; wave computes k16 slices 2kq,2kq+1 ----
    #pragma unroll
    for (int ph = 0; ph < 16; ++ph) {
        if (ph < 14) {                        // issue stage(ph+2)
            const int bo = ((ph + 2) & 3) * 24576;
            GLOAD16(gA0 + (ph + 2) * 256, smem + bo + ldsA0);
            GLOAD16(gA1 + (ph + 2) * 256, smem + bo + ldsA1);
            GLOAD16(gB  + (ph + 2) * 256, smem + bo + ldsB);
        }
        if (ph < 14)       asm volatile("s_waitcnt vmcnt(6)" ::: "memory");
        else if (ph == 14) asm volatile("s_waitcnt vmcnt(3)" ::: "memory");
        else               asm volatile("s_waitcnt vmcnt(0)" ::: "memory");
        __builtin_amdgcn_s_barrier();         // all waves' stage(ph) visible
        __builtin_amdgcn_sched_barrier(0);    // keep reads below barrier

        const int bb = (ph & 3) * 24576;
        #pragma unroll
        for (int sl = 0; sl < 2; ++sl) {
            const int c = kq * 4 + sl * 2 + h;    // 16B chunk in 256B row
            bf16x8 a = *(const bf16x8*)(smem + bb + rA * 256
                                        + ((c ^ (rA & 15)) << 4));
            bf16x8 b = *(const bf16x8*)(smem + bb + 16384 + rBn * 256
                                        + ((c ^ (rBn & 15)) << 4));
            acc = __builtin_amdgcn_mfma_f32_32x32x16_bf16(a, b, acc, 0, 0, 0);
        }
    }

    __syncthreads();                          // all reads done; reuse smem

    // ---- write kq-partials: plane (s*4+kq), [32 row][32 col] f32 = 32KB ----
    {
        float* pf = (float*)smem;
        const int plane = (s * 4 + kq) * 1024;
        #pragma unroll
        for (int reg = 0; reg < 16; ++reg) {
            int row = (reg & 3) + 8 * (reg >> 2) + 4 * h;   // verified C-layout
            pf[plane + row * 32 + (lane & 31)] = acc[reg];
        }
    }
    __syncthreads();

    // ---- reduce 4 kq-planes + epilogue. thread -> (s2, rr, 4 cols) ----
    {
        const int s2 = tid >> 8, rr = (tid >> 3) & 31, c4 = (tid & 7) * 4;
        const float4* pf4 = (const float4*)smem;
        int base = ((s2 * 4) * 1024 + rr * 32 + c4) >> 2;   // float4 index
        float4 v0 = pf4[base], v1 = pf4[base + 256];
        float4 v2 = pf4[base + 512], v3 = pf4[base + 768];
        float sum[4] = {v0.x + v1.x + v2.x + v3.x, v0.y + v1.y + v2.y + v3.y,
                        v0.z + v1.z + v2.z + v3.z, v0.w + v1.w + v2.w + v3.w};

        const int mloc = s2 * 32 + rr;
        const int m = mbase + mloc;
        const int n0 = nbase + c4;
        size_t xo = ((size_t)m << 8) + n0;
        float4 xv = *(const float4*)(x + xo);
        float4 pv = make_float4(0.f, 0.f, 0.f, 0.f);
        if (with_input) pv = *(const float4*)(patterns + xo);
        float wsc = (w_out[m] != 0.0f) ? (1.0f / (float)NN) : 0.0f;

        float xn[4] = {xv.x + DT_C * (sum[0] + pv.x - xv.x),
                       xv.y + DT_C * (sum[1] + pv.y - xv.y),
                       xv.z + DT_C * (sum[2] + pv.z - xv.z),
                       xv.w + DT_C * (sum[3] + pv.w - xv.w)};
        *(float4*)(x + xo) = make_float4(xn[0], xn[1], xn[2], xn[3]);

        const int pos = (mloc & ~15) + kperm16(mloc & 15);
        #pragma unroll
        for (int j = 0; j < 4; ++j) {
            float r = 0.5f * (1.0f + tanhf(xn[j]));
            if (wsc != 0.0f)
                atomicAdd(&out[(size_t)(n0 + j) * T + t], r * wsc);
            int nloc = c4 + j;
            int byte = 32768 + nloc * 128
                     + (((pos >> 3) ^ (nloc & 7)) << 4) + (pos & 7) * 2;
            *(unsigned short*)(smem + byte) = bf16rne(r);
        }
    }
    __syncthreads();
    if (tid < 256) {   // linear write-out of the block's [32 n][64 m] slab
        int nl = tid >> 3, pc = tid & 7;
        uint4 v = *(const uint4*)(smem + 32768 + nl * 128 + ((pc ^ (nl & 7)) << 4));
        *(uint4*)((char*)rout + (((size_t)(nbase + nl)) << 12) + mbase * 2 + pc * 16) = v;
    }
}

extern "C" void kernel_launch(void* const* d_in, const int* in_sizes, int n_in,
                              void* d_out, int out_size, void* d_ws, size_t ws_size,
                              hipStream_t stream) {
    const float* patterns = (const float*)d_in[0];   // [N, P]
    const float* J        = (const float*)d_in[1];   // [N, N]
    const float* w_out    = (const float*)d_in[2];   // [N]
    float* out            = (float*)d_out;           // [P, T]

    int T = out_size / PP;                           // 200

    size_t off = 0;
    auto alloc = [&](size_t bytes) {
        void* p = (char*)d_ws + off;
        off += (bytes + 255) & ~(size_t)255;
        return p;
    };
    unsigned short* Jp = (unsigned short*)alloc((size_t)NN * NN * 2);  // 8MB
    unsigned short* r0 = (unsigned short*)alloc((size_t)PP * NN * 2);  // 1MB
    unsigned short* r1 = (unsigned short*)alloc((size_t)PP * NN * 2);  // 1MB
    float*          x  = (float*)         alloc((size_t)NN * PP * 4);  // 2MB
    (void)ws_size; (void)n_in; (void)in_sizes;

    convert_J_kernel<<<(NN * NN) / 256, 256, 0, stream>>>(J, Jp);
    init_kernel<<<(NN * PP) / 256, 256, 0, stream>>>(x, r0, out, PP * T);

    for (int t = 0; t < T; ++t) {
        const unsigned short* rin = (t & 1) ? r1 : r0;
        unsigned short*      rout = (t & 1) ? r0 : r1;
        gemm_step_kernel<<<256, 512, 0, stream>>>(Jp, rin, rout, x, patterns,
                                                  w_out, out, t, T,
                                                  (t < ON_TIME_C) ? 1 : 0);
    }
}